// Round 9
// baseline (1347.902 us; speedup 1.0000x reference)
//
#include <hip/hip_runtime.h>
#include <cmath>

#define GS_LOOP(i, n) for (int i = blockIdx.x * blockDim.x + threadIdx.x; i < (n); i += gridDim.x * blockDim.x)

constexpr int NUSERS = 50000;
constexpr int NNODES = 100000;
constexpr int EMBD   = 128;
constexpr int NEDGE  = 2000000;
constexpr int NSCAN  = (NNODES + 1023) / 1024;   // 98

typedef float          v4f   __attribute__((ext_vector_type(4)));
typedef unsigned short v4u16 __attribute__((ext_vector_type(4)));

__device__ __forceinline__ float bf2f(unsigned short u) {
  union { unsigned int i; float f; } v; v.i = ((unsigned int)u) << 16; return v.f;
}
__device__ __forceinline__ unsigned short f2bf(float x) {
  union { float f; unsigned int i; } v; v.f = x;
  unsigned int r = v.i + 0x7FFFu + ((v.i >> 16) & 1u);   // round to nearest even
  return (unsigned short)(r >> 16);
}

// ---------------- init (row-oriented): ego0 + Pb0 + Tnb0 in one read ----------------
__global__ __launch_bounds__(256) void init_k(const float4* __restrict__ ue4,
                                              const float4* __restrict__ ie4,
                                              float4* __restrict__ ego0,
                                              ushort4* __restrict__ Pb0,
                                              ushort4* __restrict__ Tnb0) {
  const int j = threadIdx.x & 31;
  const int u = blockIdx.x * 8 + (threadIdx.x >> 5);
  if (u >= NNODES) return;
  const float4 y = (u < NUSERS) ? ue4[(size_t)u * 32 + j]
                                : ie4[(size_t)(u - NUSERS) * 32 + j];
  ego0[(size_t)u * 32 + j] = y;
  Pb0[(size_t)u * 32 + j] = make_ushort4(f2bf(y.x), f2bf(y.y), f2bf(y.z), f2bf(y.w));
  float ss = y.x * y.x + y.y * y.y + y.z * y.z + y.w * y.w;
  ss += __shfl_xor(ss, 1, 64);
  ss += __shfl_xor(ss, 2, 64);
  ss += __shfl_xor(ss, 4, 64);                  // 8-lane factor-group reduce
  const float inv = 1.f / fmaxf(sqrtf(ss), 1e-12f);
  Tnb0[(size_t)u * 32 + j] = make_ushort4(f2bf(tanhf(y.x * inv)), f2bf(tanhf(y.y * inv)),
                                          f2bf(tanhf(y.z * inv)), f2bf(tanhf(y.w * inv)));
}

// ---------------- CSR build ----------------
__global__ void hist_k(const int* __restrict__ h, int* __restrict__ counts) {
  GS_LOOP(e, NEDGE) atomicAdd(&counts[h[e]], 1);
}

// hierarchical scan: per-block inclusive scan + block sums
__global__ __launch_bounds__(1024) void scan1_k(const int* __restrict__ counts,
                                                int* __restrict__ part,
                                                int* __restrict__ bsum) {
  __shared__ int wsum[16];
  const int tid = threadIdx.x, lane = tid & 63, wid = tid >> 6;
  const int i = blockIdx.x * 1024 + tid;
  int v = (i < NNODES) ? counts[i] : 0;
  #pragma unroll
  for (int off = 1; off < 64; off <<= 1) {
    int y = __shfl_up(v, off, 64);
    if (lane >= off) v += y;
  }
  if (lane == 63) wsum[wid] = v;
  __syncthreads();
  if (wid == 0) {
    int w = (lane < 16) ? wsum[lane] : 0;
    #pragma unroll
    for (int off = 1; off < 16; off <<= 1) {
      int y = __shfl_up(w, off, 64);
      if (lane >= off) w += y;
    }
    if (lane < 16) wsum[lane] = w;
  }
  __syncthreads();
  const int incl = v + (wid ? wsum[wid - 1] : 0);
  if (i < NNODES) part[i] = incl;
  if (tid == 1023) bsum[blockIdx.x] = incl;
}

__global__ __launch_bounds__(128) void scan2_k(const int* __restrict__ bsum,
                                               int* __restrict__ boff) {
  __shared__ int s0[128], s1[128];
  const int tid = threadIdx.x;
  s0[tid] = (tid < NSCAN) ? bsum[tid] : 0;
  __syncthreads();
  int* a = s0; int* b = s1;
  for (int off = 1; off < 128; off <<= 1) {
    const int val = a[tid] + ((tid >= off) ? a[tid - off] : 0);
    b[tid] = val;
    __syncthreads();
    int* tmp = a; a = b; b = tmp;
  }
  boff[tid] = (tid == 0) ? 0 : a[tid - 1];
}

// also derives pass-0 d_inv analytically: softmax(ones)=0.25 -> deg0 = 0.25*count
__global__ __launch_bounds__(1024) void scan3_k(const int* __restrict__ part,
                                                const int* __restrict__ boff,
                                                const int* __restrict__ counts,
                                                int* __restrict__ row_ptr,
                                                float* __restrict__ dv0) {
  const int i = blockIdx.x * 1024 + threadIdx.x;
  if (i < NNODES) {
    row_ptr[i + 1] = part[i] + boff[blockIdx.x];
    const float d = rsqrtf(fmaxf(0.25f * (float)counts[i], 1e-12f));
    v4f w = {d, d, d, d};
    *((v4f*)dv0 + i) = w;
  }
  if (i == 0) row_ptr[0] = 0;
}

// edge identity irrelevant downstream (A lives in CSR order): store only t
__global__ void fill_k(const int* __restrict__ h, const int* __restrict__ t,
                       const int* __restrict__ row_ptr, int* __restrict__ cur,
                       int* __restrict__ csr_t) {
  GS_LOOP(e, NEDGE) {
    int u = h[e];
    int pos = row_ptr[u] + atomicAdd(&cur[u], 1);
    csr_t[pos] = t[e];
  }
}

// sort each row's tails ascending (once): makes gather streams sweep node-space
// monotonically -> co-resident blocks reuse Pb/Tnb lines in L2 instead of thrashing
__global__ void sort_k(const int* __restrict__ row_ptr, int* __restrict__ csr_t) {
  GS_LOOP(u, NNODES) {
    const int beg = row_ptr[u], end = row_ptr[u + 1];
    for (int i = beg + 1; i < end; ++i) {
      const int v = csr_t[i];
      int k = i - 1;
      while (k >= beg && csr_t[k] > v) { csr_t[k + 1] = csr_t[k]; --k; }
      csr_t[k + 1] = v;
    }
  }
}

// ---------------- per-pass: softmax(A)->c (csr order) + d_inv, 16 lanes/node ----------------
__global__ __launch_bounds__(256) void deg_sm_k(const float* __restrict__ A,
                                                const int* __restrict__ row_ptr,
                                                float* __restrict__ c,
                                                float* __restrict__ dv) {
  const float4* A4 = (const float4*)A;
  float4* c4 = (float4*)c;
  const int g = threadIdx.x >> 4;
  const int lane16 = threadIdx.x & 15;
  const int u = blockIdx.x * 16 + g;
  if (u >= NNODES) return;
  const int beg = row_ptr[u], end = row_ptr[u + 1];
  float4 acc = make_float4(0.f, 0.f, 0.f, 0.f);
  for (int p = beg + lane16; p < end; p += 16) {
    float4 a = A4[p];
    float m = fmaxf(fmaxf(a.x, a.y), fmaxf(a.z, a.w));
    float e0 = __expf(a.x - m), e1 = __expf(a.y - m);
    float e2 = __expf(a.z - m), e3 = __expf(a.w - m);
    float inv = 1.f / (e0 + e1 + e2 + e3);
    float4 s = make_float4(e0 * inv, e1 * inv, e2 * inv, e3 * inv);
    c4[p] = s;
    acc.x += s.x; acc.y += s.y; acc.z += s.z; acc.w += s.w;
  }
  #pragma unroll
  for (int m = 1; m < 16; m <<= 1) {
    acc.x += __shfl_xor(acc.x, m, 64);
    acc.y += __shfl_xor(acc.y, m, 64);
    acc.z += __shfl_xor(acc.z, m, 64);
    acc.w += __shfl_xor(acc.w, m, 64);
  }
  if (lane16 == 0)
    ((float4*)dv)[u] = make_float4(rsqrtf(fmaxf(acc.x, 1e-12f)),
                                   rsqrtf(fmaxf(acc.y, 1e-12f)),
                                   rsqrtf(fmaxf(acc.z, 1e-12f)),
                                   rsqrtf(fmaxf(acc.w, 1e-12f)));
}

// ---------------- fused propagate + score update (wave per node, bf16 gathers) ----------------
// MODE: 0 = score only; 1 = score + write Q(f32) + Pb1/Tnb1 tables; 2 = mean output to o1
// FIRST: pass 0 (A implicitly 1.0, scores uniform 0.25, c never read)
template <int MODE, bool FIRST>
__global__ __launch_bounds__(256) void prop_k(
    const ushort4* __restrict__ Pb4, float4* __restrict__ Q4,
    const float* __restrict__ dv_in, const int* __restrict__ row_ptr,
    const int* __restrict__ csr_t, const float* __restrict__ c,
    float* __restrict__ A, const ushort4* __restrict__ Tnb4,
    const float4* __restrict__ e0_4, const float4* __restrict__ e1_4,
    float4* __restrict__ o1_4, ushort4* __restrict__ Pb1w,
    ushort4* __restrict__ Tnb1w) {
  const int u = blockIdx.x * 4 + (threadIdx.x >> 6);
  const int l = threadIdx.x & 63;
  const int half = l >> 5;     // which of 2 edges per iteration
  const int j = l & 31;        // float4 column
  const int f = j >> 3;        // factor
  const int beg = row_ptr[u], end = row_ptr[u + 1];

  // loop 1: x[u] = d_inv[u] * sum_p c[p][f] * d_inv[t_p][f] * Pb[t_p]
  float4 acc = make_float4(0.f, 0.f, 0.f, 0.f);
  int p = beg + half;
  for (; p + 14 < end; p += 16) {              // manual unroll x8: 8 row gathers in flight
    const int t0 = csr_t[p],      t1 = csr_t[p + 2];
    const int t2 = csr_t[p + 4],  t3 = csr_t[p + 6];
    const int t4 = csr_t[p + 8],  t5 = csr_t[p + 10];
    const int t6 = csr_t[p + 12], t7 = csr_t[p + 14];
    const ushort4 y0 = Pb4[(size_t)t0 * 32 + j];
    const ushort4 y1 = Pb4[(size_t)t1 * 32 + j];
    const ushort4 y2 = Pb4[(size_t)t2 * 32 + j];
    const ushort4 y3 = Pb4[(size_t)t3 * 32 + j];
    const ushort4 y4 = Pb4[(size_t)t4 * 32 + j];
    const ushort4 y5 = Pb4[(size_t)t5 * 32 + j];
    const ushort4 y6 = Pb4[(size_t)t6 * 32 + j];
    const ushort4 y7 = Pb4[(size_t)t7 * 32 + j];
    const float c0 = (FIRST ? 0.25f : __builtin_nontemporal_load(c + (size_t)p * 4 + f))        * dv_in[t0 * 4 + f];
    const float c1 = (FIRST ? 0.25f : __builtin_nontemporal_load(c + (size_t)(p + 2) * 4 + f))  * dv_in[t1 * 4 + f];
    const float c2 = (FIRST ? 0.25f : __builtin_nontemporal_load(c + (size_t)(p + 4) * 4 + f))  * dv_in[t2 * 4 + f];
    const float c3 = (FIRST ? 0.25f : __builtin_nontemporal_load(c + (size_t)(p + 6) * 4 + f))  * dv_in[t3 * 4 + f];
    const float c4_ = (FIRST ? 0.25f : __builtin_nontemporal_load(c + (size_t)(p + 8) * 4 + f)) * dv_in[t4 * 4 + f];
    const float c5 = (FIRST ? 0.25f : __builtin_nontemporal_load(c + (size_t)(p + 10) * 4 + f)) * dv_in[t5 * 4 + f];
    const float c6 = (FIRST ? 0.25f : __builtin_nontemporal_load(c + (size_t)(p + 12) * 4 + f)) * dv_in[t6 * 4 + f];
    const float c7 = (FIRST ? 0.25f : __builtin_nontemporal_load(c + (size_t)(p + 14) * 4 + f)) * dv_in[t7 * 4 + f];
    acc.x += c0 * bf2f(y0.x) + c1 * bf2f(y1.x) + c2 * bf2f(y2.x) + c3 * bf2f(y3.x)
           + c4_ * bf2f(y4.x) + c5 * bf2f(y5.x) + c6 * bf2f(y6.x) + c7 * bf2f(y7.x);
    acc.y += c0 * bf2f(y0.y) + c1 * bf2f(y1.y) + c2 * bf2f(y2.y) + c3 * bf2f(y3.y)
           + c4_ * bf2f(y4.y) + c5 * bf2f(y5.y) + c6 * bf2f(y6.y) + c7 * bf2f(y7.y);
    acc.z += c0 * bf2f(y0.z) + c1 * bf2f(y1.z) + c2 * bf2f(y2.z) + c3 * bf2f(y3.z)
           + c4_ * bf2f(y4.z) + c5 * bf2f(y5.z) + c6 * bf2f(y6.z) + c7 * bf2f(y7.z);
    acc.w += c0 * bf2f(y0.w) + c1 * bf2f(y1.w) + c2 * bf2f(y2.w) + c3 * bf2f(y3.w)
           + c4_ * bf2f(y4.w) + c5 * bf2f(y5.w) + c6 * bf2f(y6.w) + c7 * bf2f(y7.w);
  }
  for (; p < end; p += 2) {                    // tail
    const int tn = csr_t[p];
    const float cf = (FIRST ? 0.25f : __builtin_nontemporal_load(c + (size_t)p * 4 + f)) * dv_in[tn * 4 + f];
    const ushort4 y = Pb4[(size_t)tn * 32 + j];
    acc.x += cf * bf2f(y.x); acc.y += cf * bf2f(y.y);
    acc.z += cf * bf2f(y.z); acc.w += cf * bf2f(y.w);
  }
  acc.x += __shfl_xor(acc.x, 32, 64);
  acc.y += __shfl_xor(acc.y, 32, 64);
  acc.z += __shfl_xor(acc.z, 32, 64);
  acc.w += __shfl_xor(acc.w, 32, 64);
  const float du = dv_in[u * 4 + f];
  const float4 x = make_float4(acc.x * du, acc.y * du, acc.z * du, acc.w * du);

  if (MODE == 2) {                             // final pass: write mean(e0,e1,x) to o1
    if (half == 0) {
      const v4f a = __builtin_nontemporal_load((const v4f*)e0_4 + (size_t)u * 32 + j);
      const v4f b = __builtin_nontemporal_load((const v4f*)e1_4 + (size_t)u * 32 + j);
      v4f r = {(a.x + b.x + x.x) * (1.f / 3.f), (a.y + b.y + x.y) * (1.f / 3.f),
               (a.z + b.z + x.z) * (1.f / 3.f), (a.w + b.w + x.w) * (1.f / 3.f)};
      __builtin_nontemporal_store(r, (v4f*)o1_4 + (size_t)u * 32 + j);
    }
    return;
  }
  if (MODE == 1 && half == 0) {
    v4f xq = {x.x, x.y, x.z, x.w};
    __builtin_nontemporal_store(xq, (v4f*)Q4 + (size_t)u * 32 + j);
    v4u16 pb = {f2bf(x.x), f2bf(x.y), f2bf(x.z), f2bf(x.w)};
    __builtin_nontemporal_store(pb, (v4u16*)Pb1w + (size_t)u * 32 + j);
  }

  // chunk l2-norm of x (8-lane factor group)
  float ss = x.x * x.x + x.y * x.y + x.z * x.z + x.w * x.w;
  ss += __shfl_xor(ss, 1, 64);
  ss += __shfl_xor(ss, 2, 64);
  ss += __shfl_xor(ss, 4, 64);
  const float inv = 1.f / fmaxf(sqrtf(ss), 1e-12f);
  const float4 xn = make_float4(x.x * inv, x.y * inv, x.z * inv, x.w * inv);
  if (MODE == 1 && half == 0) {
    v4u16 tb = {f2bf(tanhf(xn.x)), f2bf(tanhf(xn.y)), f2bf(tanhf(xn.z)), f2bf(tanhf(xn.w))};
    __builtin_nontemporal_store(tb, (v4u16*)Tnb1w + (size_t)u * 32 + j);
  }

  // loop 2: A[p][f] += dot(xn_chunk, Tnb[t]_chunk)  (sequential A writes, no atomics)
  int q = beg + half;
  for (; q + 6 < end; q += 8) {                // manual unroll x4
    const int t0 = csr_t[q],     t1 = csr_t[q + 2];
    const int t2 = csr_t[q + 4], t3 = csr_t[q + 6];
    const ushort4 b0 = Tnb4[(size_t)t0 * 32 + j];
    const ushort4 b1 = Tnb4[(size_t)t1 * 32 + j];
    const ushort4 b2 = Tnb4[(size_t)t2 * 32 + j];
    const ushort4 b3 = Tnb4[(size_t)t3 * 32 + j];
    float s0 = xn.x * bf2f(b0.x) + xn.y * bf2f(b0.y) + xn.z * bf2f(b0.z) + xn.w * bf2f(b0.w);
    float s1 = xn.x * bf2f(b1.x) + xn.y * bf2f(b1.y) + xn.z * bf2f(b1.z) + xn.w * bf2f(b1.w);
    float s2 = xn.x * bf2f(b2.x) + xn.y * bf2f(b2.y) + xn.z * bf2f(b2.z) + xn.w * bf2f(b2.w);
    float s3 = xn.x * bf2f(b3.x) + xn.y * bf2f(b3.y) + xn.z * bf2f(b3.z) + xn.w * bf2f(b3.w);
    #pragma unroll
    for (int m = 1; m < 8; m <<= 1) {
      s0 += __shfl_xor(s0, m, 64); s1 += __shfl_xor(s1, m, 64);
      s2 += __shfl_xor(s2, m, 64); s3 += __shfl_xor(s3, m, 64);
    }
    if ((j & 7) == 0) {
      if (FIRST) {
        A[(size_t)q * 4 + f] = 1.f + s0;
        A[(size_t)(q + 2) * 4 + f] = 1.f + s1;
        A[(size_t)(q + 4) * 4 + f] = 1.f + s2;
        A[(size_t)(q + 6) * 4 + f] = 1.f + s3;
      } else {
        A[(size_t)q * 4 + f] += s0;
        A[(size_t)(q + 2) * 4 + f] += s1;
        A[(size_t)(q + 4) * 4 + f] += s2;
        A[(size_t)(q + 6) * 4 + f] += s3;
      }
    }
  }
  for (; q < end; q += 2) {                    // tail
    const int tn = csr_t[q];
    const ushort4 tb = Tnb4[(size_t)tn * 32 + j];
    float s = xn.x * bf2f(tb.x) + xn.y * bf2f(tb.y) + xn.z * bf2f(tb.z) + xn.w * bf2f(tb.w);
    s += __shfl_xor(s, 1, 64);
    s += __shfl_xor(s, 2, 64);
    s += __shfl_xor(s, 4, 64);
    if ((j & 7) == 0) {
      if (FIRST) A[(size_t)q * 4 + f] = 1.f + s;
      else       A[(size_t)q * 4 + f] += s;
    }
  }
}

extern "C" void kernel_launch(void* const* d_in, const int* in_sizes, int n_in,
                              void* d_out, int out_size, void* d_ws, size_t ws_size,
                              hipStream_t stream) {
  const float* ue = (const float*)d_in[0];
  const float* ie = (const float*)d_in[1];
  const int* h = (const int*)d_in[2];
  const int* t = (const int*)d_in[3];
  float* out = (float*)d_out;
  char* ws = (char*)d_ws;

  size_t off = 0;
  auto alloc = [&](size_t bytes) -> void* {
    void* p = ws + off;
    off += (bytes + 255) & ~size_t(255);
    return p;
  };
  float* ego0  = (float*)alloc(sizeof(float) * (size_t)NNODES * EMBD);  // 51.2 MB
  float* ego1  = (float*)alloc(sizeof(float) * (size_t)NNODES * EMBD);  // 51.2 MB
  float* A     = (float*)alloc(sizeof(float) * 4 * (size_t)NEDGE);      // 32  MB (CSR order)
  float* c     = (float*)alloc(sizeof(float) * 4 * (size_t)NEDGE);      // 32  MB (CSR order)
  float* dvA   = (float*)alloc(sizeof(float) * NNODES * 4);             // 1.6 MB (ping)
  float* dvB   = (float*)alloc(sizeof(float) * NNODES * 4);             // 1.6 MB (pong)
  int* row_ptr = (int*)alloc(sizeof(int) * (NNODES + 1));
  int* cur     = (int*)alloc(sizeof(int) * NNODES);
  int* part    = (int*)alloc(sizeof(int) * NNODES);
  int* bsum    = (int*)alloc(sizeof(int) * 128);
  int* boff    = (int*)alloc(sizeof(int) * 128);
  int* csr_t   = (int*)alloc(sizeof(int) * NEDGE);                      // 8 MB

  // bf16 gather tables live in d_out (each half = 51.2 MB = Pb(25.6) + Tnb(25.6)).
  // Layer-1 tables in o1 (dead by pass 3, which overwrites o1);
  // layer-2 tables in o2 (read during pass 3; o2 refilled by the final d2d copy).
  float* o1 = out;
  float* o2 = out + (size_t)NNODES * EMBD;
  ushort4* Pb0  = (ushort4*)o1;
  ushort4* Tnb0 = (ushort4*)((char*)o1 + sizeof(unsigned short) * (size_t)NNODES * EMBD);
  ushort4* Pb1  = (ushort4*)o2;
  ushort4* Tnb1 = (ushort4*)((char*)o2 + sizeof(unsigned short) * (size_t)NNODES * EMBD);

  // setup (once per call)
  init_k<<<(NNODES + 7) / 8, 256, 0, stream>>>((const float4*)ue, (const float4*)ie,
                                               (float4*)ego0, Pb0, Tnb0);
  hipMemsetAsync(cur, 0, sizeof(int) * NNODES, stream);
  hist_k<<<2048, 256, 0, stream>>>(h, cur);
  scan1_k<<<NSCAN, 1024, 0, stream>>>(cur, part, bsum);
  scan2_k<<<1, 128, 0, stream>>>(bsum, boff);
  scan3_k<<<NSCAN, 1024, 0, stream>>>(part, boff, cur, row_ptr, dvA);
  hipMemsetAsync(cur, 0, sizeof(int) * NNODES, stream);
  fill_k<<<2048, 256, 0, stream>>>(h, t, row_ptr, cur, csr_t);
  sort_k<<<512, 256, 0, stream>>>(row_ptr, csr_t);

  // pass 0: score (analytic softmax=0.25, dv from counts)  [layer-1 tables]
  // pass 1: deg_sm(A)->c,dvB; score + Q=ego1 + Pb1/Tnb1    [layer-1 tables]
  // pass 2: deg_sm(A)->c,dvA; score                        [layer-2 tables]
  // pass 3: deg_sm(A)->c,dvB; mean output -> o1            [layer-2 tables]
  prop_k<0, true><<<NNODES / 4, 256, 0, stream>>>(
      Pb0, (float4*)ego1, dvA, row_ptr, csr_t, c, A, Tnb0,
      (const float4*)ego0, (const float4*)ego1, (float4*)o1, Pb1, Tnb1);

  deg_sm_k<<<(NNODES + 15) / 16, 256, 0, stream>>>(A, row_ptr, c, dvB);
  prop_k<1, false><<<NNODES / 4, 256, 0, stream>>>(
      Pb0, (float4*)ego1, dvB, row_ptr, csr_t, c, A, Tnb0,
      (const float4*)ego0, (const float4*)ego1, (float4*)o1, Pb1, Tnb1);

  deg_sm_k<<<(NNODES + 15) / 16, 256, 0, stream>>>(A, row_ptr, c, dvA);
  prop_k<0, false><<<NNODES / 4, 256, 0, stream>>>(
      Pb1, (float4*)ego1, dvA, row_ptr, csr_t, c, A, Tnb1,
      (const float4*)ego0, (const float4*)ego1, (float4*)o1, Pb1, Tnb1);

  deg_sm_k<<<(NNODES + 15) / 16, 256, 0, stream>>>(A, row_ptr, c, dvB);
  prop_k<2, false><<<NNODES / 4, 256, 0, stream>>>(
      Pb1, (float4*)ego1, dvB, row_ptr, csr_t, c, A, Tnb1,
      (const float4*)ego0, (const float4*)ego1, (float4*)o1, Pb1, Tnb1);

  // duplicate (u_g, i_g) into the second output pair
  hipMemcpyAsync(o2, o1, sizeof(float) * (size_t)NNODES * EMBD,
                 hipMemcpyDeviceToDevice, stream);
}

// Round 11
// 1191.097 us; speedup vs baseline: 1.1316x; 1.1316x over previous
//
#include <hip/hip_runtime.h>
#include <cmath>

#define GS_LOOP(i, n) for (int i = blockIdx.x * blockDim.x + threadIdx.x; i < (n); i += gridDim.x * blockDim.x)

constexpr int NUSERS = 50000;
constexpr int NNODES = 100000;
constexpr int EMBD   = 128;
constexpr int NEDGE  = 2000000;
constexpr int NSCAN  = (NNODES + 1023) / 1024;   // 98

typedef float          v4f   __attribute__((ext_vector_type(4)));
typedef unsigned short v4u16 __attribute__((ext_vector_type(4)));

__device__ __forceinline__ float bf2f(unsigned short u) {
  union { unsigned int i; float f; } v; v.i = ((unsigned int)u) << 16; return v.f;
}
__device__ __forceinline__ unsigned short f2bf(float x) {
  union { float f; unsigned int i; } v; v.f = x;
  unsigned int r = v.i + 0x7FFFu + ((v.i >> 16) & 1u);   // round to nearest even
  return (unsigned short)(r >> 16);
}

// ---------------- init (row-oriented): ego0 + Pb0 + Tnb0 in one read ----------------
__global__ __launch_bounds__(256) void init_k(const float4* __restrict__ ue4,
                                              const float4* __restrict__ ie4,
                                              float4* __restrict__ ego0,
                                              ushort4* __restrict__ Pb0,
                                              ushort4* __restrict__ Tnb0) {
  const int j = threadIdx.x & 31;
  const int u = blockIdx.x * 8 + (threadIdx.x >> 5);
  if (u >= NNODES) return;
  const float4 y = (u < NUSERS) ? ue4[(size_t)u * 32 + j]
                                : ie4[(size_t)(u - NUSERS) * 32 + j];
  ego0[(size_t)u * 32 + j] = y;
  Pb0[(size_t)u * 32 + j] = make_ushort4(f2bf(y.x), f2bf(y.y), f2bf(y.z), f2bf(y.w));
  float ss = y.x * y.x + y.y * y.y + y.z * y.z + y.w * y.w;
  ss += __shfl_xor(ss, 1, 64);
  ss += __shfl_xor(ss, 2, 64);
  ss += __shfl_xor(ss, 4, 64);                  // 8-lane factor-group reduce
  const float inv = 1.f / fmaxf(sqrtf(ss), 1e-12f);
  Tnb0[(size_t)u * 32 + j] = make_ushort4(f2bf(tanhf(y.x * inv)), f2bf(tanhf(y.y * inv)),
                                          f2bf(tanhf(y.z * inv)), f2bf(tanhf(y.w * inv)));
}

// ---------------- CSR build ----------------
__global__ void hist_k(const int* __restrict__ h, int* __restrict__ counts) {
  GS_LOOP(e, NEDGE) atomicAdd(&counts[h[e]], 1);
}

// hierarchical scan: per-block inclusive scan + block sums
__global__ __launch_bounds__(1024) void scan1_k(const int* __restrict__ counts,
                                                int* __restrict__ part,
                                                int* __restrict__ bsum) {
  __shared__ int wsum[16];
  const int tid = threadIdx.x, lane = tid & 63, wid = tid >> 6;
  const int i = blockIdx.x * 1024 + tid;
  int v = (i < NNODES) ? counts[i] : 0;
  #pragma unroll
  for (int off = 1; off < 64; off <<= 1) {
    int y = __shfl_up(v, off, 64);
    if (lane >= off) v += y;
  }
  if (lane == 63) wsum[wid] = v;
  __syncthreads();
  if (wid == 0) {
    int w = (lane < 16) ? wsum[lane] : 0;
    #pragma unroll
    for (int off = 1; off < 16; off <<= 1) {
      int y = __shfl_up(w, off, 64);
      if (lane >= off) w += y;
    }
    if (lane < 16) wsum[lane] = w;
  }
  __syncthreads();
  const int incl = v + (wid ? wsum[wid - 1] : 0);
  if (i < NNODES) part[i] = incl;
  if (tid == 1023) bsum[blockIdx.x] = incl;
}

__global__ __launch_bounds__(128) void scan2_k(const int* __restrict__ bsum,
                                               int* __restrict__ boff) {
  __shared__ int s0[128], s1[128];
  const int tid = threadIdx.x;
  s0[tid] = (tid < NSCAN) ? bsum[tid] : 0;
  __syncthreads();
  int* a = s0; int* b = s1;
  for (int off = 1; off < 128; off <<= 1) {
    const int val = a[tid] + ((tid >= off) ? a[tid - off] : 0);
    b[tid] = val;
    __syncthreads();
    int* tmp = a; a = b; b = tmp;
  }
  boff[tid] = (tid == 0) ? 0 : a[tid - 1];
}

// also derives pass-0 d_inv analytically: softmax(ones)=0.25 -> deg0 = 0.25*count
__global__ __launch_bounds__(1024) void scan3_k(const int* __restrict__ part,
                                                const int* __restrict__ boff,
                                                const int* __restrict__ counts,
                                                int* __restrict__ row_ptr,
                                                float* __restrict__ dv0) {
  const int i = blockIdx.x * 1024 + threadIdx.x;
  if (i < NNODES) {
    row_ptr[i + 1] = part[i] + boff[blockIdx.x];
    const float d = rsqrtf(fmaxf(0.25f * (float)counts[i], 1e-12f));
    v4f w = {d, d, d, d};
    *((v4f*)dv0 + i) = w;
  }
  if (i == 0) row_ptr[0] = 0;
}

// edge identity irrelevant downstream (A lives in CSR order): store only t
__global__ void fill_k(const int* __restrict__ h, const int* __restrict__ t,
                       const int* __restrict__ row_ptr, int* __restrict__ cur,
                       int* __restrict__ csr_t) {
  GS_LOOP(e, NEDGE) {
    int u = h[e];
    int pos = row_ptr[u] + atomicAdd(&cur[u], 1);
    csr_t[pos] = t[e];
  }
}

// ---------------- per-pass: softmax(A)->c (bf16, csr order) + d_inv, 16 lanes/node ----------------
__global__ __launch_bounds__(256) void deg_sm_k(const float* __restrict__ A,
                                                const int* __restrict__ row_ptr,
                                                unsigned short* __restrict__ c,
                                                float* __restrict__ dv) {
  const float4* A4 = (const float4*)A;
  ushort4* c4 = (ushort4*)c;
  const int g = threadIdx.x >> 4;
  const int lane16 = threadIdx.x & 15;
  const int u = blockIdx.x * 16 + g;
  if (u >= NNODES) return;
  const int beg = row_ptr[u], end = row_ptr[u + 1];
  float4 acc = make_float4(0.f, 0.f, 0.f, 0.f);
  for (int p = beg + lane16; p < end; p += 16) {
    float4 a = A4[p];
    float m = fmaxf(fmaxf(a.x, a.y), fmaxf(a.z, a.w));
    float e0 = __expf(a.x - m), e1 = __expf(a.y - m);
    float e2 = __expf(a.z - m), e3 = __expf(a.w - m);
    float inv = 1.f / (e0 + e1 + e2 + e3);
    float4 s = make_float4(e0 * inv, e1 * inv, e2 * inv, e3 * inv);
    c4[p] = make_ushort4(f2bf(s.x), f2bf(s.y), f2bf(s.z), f2bf(s.w));
    acc.x += s.x; acc.y += s.y; acc.z += s.z; acc.w += s.w;
  }
  #pragma unroll
  for (int m = 1; m < 16; m <<= 1) {
    acc.x += __shfl_xor(acc.x, m, 64);
    acc.y += __shfl_xor(acc.y, m, 64);
    acc.z += __shfl_xor(acc.z, m, 64);
    acc.w += __shfl_xor(acc.w, m, 64);
  }
  if (lane16 == 0)
    ((float4*)dv)[u] = make_float4(rsqrtf(fmaxf(acc.x, 1e-12f)),
                                   rsqrtf(fmaxf(acc.y, 1e-12f)),
                                   rsqrtf(fmaxf(acc.z, 1e-12f)),
                                   rsqrtf(fmaxf(acc.w, 1e-12f)));
}

// ---------------- fused propagate + score update (wave per node, bf16 gathers) ----------------
// MODE: 0 = score only; 1 = score + write Q(f32) + Pb1/Tnb1 tables; 2 = mean output to o1
// FIRST: pass 0 (A implicitly 1.0, scores uniform 0.25, c never read)
template <int MODE, bool FIRST>
__global__ __launch_bounds__(256) void prop_k(
    const ushort4* __restrict__ Pb4, float4* __restrict__ Q4,
    const float* __restrict__ dv_in, const int* __restrict__ row_ptr,
    const int* __restrict__ csr_t, const unsigned short* __restrict__ c,
    float* __restrict__ A, const ushort4* __restrict__ Tnb4,
    const float4* __restrict__ e0_4, const float4* __restrict__ e1_4,
    float4* __restrict__ o1_4, ushort4* __restrict__ Pb1w,
    ushort4* __restrict__ Tnb1w) {
  const int u = blockIdx.x * 4 + (threadIdx.x >> 6);
  const int l = threadIdx.x & 63;
  const int half = l >> 5;     // which of 2 edges per iteration
  const int j = l & 31;        // float4 column
  const int f = j >> 3;        // factor
  const int beg = row_ptr[u], end = row_ptr[u + 1];

  // loop 1: x[u] = d_inv[u] * sum_p c[p][f] * d_inv[t_p][f] * Pb[t_p]
  float4 acc = make_float4(0.f, 0.f, 0.f, 0.f);
  int p = beg + half;
  for (; p + 14 < end; p += 16) {              // manual unroll x8: 8 row gathers in flight
    const int t0 = csr_t[p],      t1 = csr_t[p + 2];
    const int t2 = csr_t[p + 4],  t3 = csr_t[p + 6];
    const int t4 = csr_t[p + 8],  t5 = csr_t[p + 10];
    const int t6 = csr_t[p + 12], t7 = csr_t[p + 14];
    const ushort4 y0 = Pb4[(size_t)t0 * 32 + j];
    const ushort4 y1 = Pb4[(size_t)t1 * 32 + j];
    const ushort4 y2 = Pb4[(size_t)t2 * 32 + j];
    const ushort4 y3 = Pb4[(size_t)t3 * 32 + j];
    const ushort4 y4 = Pb4[(size_t)t4 * 32 + j];
    const ushort4 y5 = Pb4[(size_t)t5 * 32 + j];
    const ushort4 y6 = Pb4[(size_t)t6 * 32 + j];
    const ushort4 y7 = Pb4[(size_t)t7 * 32 + j];
    const float c0 = (FIRST ? 0.25f : bf2f(__builtin_nontemporal_load(c + (size_t)p * 4 + f)))        * dv_in[t0 * 4 + f];
    const float c1 = (FIRST ? 0.25f : bf2f(__builtin_nontemporal_load(c + (size_t)(p + 2) * 4 + f)))  * dv_in[t1 * 4 + f];
    const float c2 = (FIRST ? 0.25f : bf2f(__builtin_nontemporal_load(c + (size_t)(p + 4) * 4 + f)))  * dv_in[t2 * 4 + f];
    const float c3 = (FIRST ? 0.25f : bf2f(__builtin_nontemporal_load(c + (size_t)(p + 6) * 4 + f)))  * dv_in[t3 * 4 + f];
    const float c4_ = (FIRST ? 0.25f : bf2f(__builtin_nontemporal_load(c + (size_t)(p + 8) * 4 + f))) * dv_in[t4 * 4 + f];
    const float c5 = (FIRST ? 0.25f : bf2f(__builtin_nontemporal_load(c + (size_t)(p + 10) * 4 + f))) * dv_in[t5 * 4 + f];
    const float c6 = (FIRST ? 0.25f : bf2f(__builtin_nontemporal_load(c + (size_t)(p + 12) * 4 + f))) * dv_in[t6 * 4 + f];
    const float c7 = (FIRST ? 0.25f : bf2f(__builtin_nontemporal_load(c + (size_t)(p + 14) * 4 + f))) * dv_in[t7 * 4 + f];
    acc.x += c0 * bf2f(y0.x) + c1 * bf2f(y1.x) + c2 * bf2f(y2.x) + c3 * bf2f(y3.x)
           + c4_ * bf2f(y4.x) + c5 * bf2f(y5.x) + c6 * bf2f(y6.x) + c7 * bf2f(y7.x);
    acc.y += c0 * bf2f(y0.y) + c1 * bf2f(y1.y) + c2 * bf2f(y2.y) + c3 * bf2f(y3.y)
           + c4_ * bf2f(y4.y) + c5 * bf2f(y5.y) + c6 * bf2f(y6.y) + c7 * bf2f(y7.y);
    acc.z += c0 * bf2f(y0.z) + c1 * bf2f(y1.z) + c2 * bf2f(y2.z) + c3 * bf2f(y3.z)
           + c4_ * bf2f(y4.z) + c5 * bf2f(y5.z) + c6 * bf2f(y6.z) + c7 * bf2f(y7.z);
    acc.w += c0 * bf2f(y0.w) + c1 * bf2f(y1.w) + c2 * bf2f(y2.w) + c3 * bf2f(y3.w)
           + c4_ * bf2f(y4.w) + c5 * bf2f(y5.w) + c6 * bf2f(y6.w) + c7 * bf2f(y7.w);
  }
  for (; p < end; p += 2) {                    // tail
    const int tn = csr_t[p];
    const float cf = (FIRST ? 0.25f : bf2f(__builtin_nontemporal_load(c + (size_t)p * 4 + f))) * dv_in[tn * 4 + f];
    const ushort4 y = Pb4[(size_t)tn * 32 + j];
    acc.x += cf * bf2f(y.x); acc.y += cf * bf2f(y.y);
    acc.z += cf * bf2f(y.z); acc.w += cf * bf2f(y.w);
  }
  acc.x += __shfl_xor(acc.x, 32, 64);
  acc.y += __shfl_xor(acc.y, 32, 64);
  acc.z += __shfl_xor(acc.z, 32, 64);
  acc.w += __shfl_xor(acc.w, 32, 64);
  const float du = dv_in[u * 4 + f];
  const float4 x = make_float4(acc.x * du, acc.y * du, acc.z * du, acc.w * du);

  if (MODE == 2) {                             // final pass: write mean(e0,e1,x) to o1
    if (half == 0) {
      const v4f a = __builtin_nontemporal_load((const v4f*)e0_4 + (size_t)u * 32 + j);
      const v4f b = __builtin_nontemporal_load((const v4f*)e1_4 + (size_t)u * 32 + j);
      v4f r = {(a.x + b.x + x.x) * (1.f / 3.f), (a.y + b.y + x.y) * (1.f / 3.f),
               (a.z + b.z + x.z) * (1.f / 3.f), (a.w + b.w + x.w) * (1.f / 3.f)};
      __builtin_nontemporal_store(r, (v4f*)o1_4 + (size_t)u * 32 + j);
    }
    return;
  }
  if (MODE == 1 && half == 0) {
    v4f xq = {x.x, x.y, x.z, x.w};
    __builtin_nontemporal_store(xq, (v4f*)Q4 + (size_t)u * 32 + j);
    v4u16 pb = {f2bf(x.x), f2bf(x.y), f2bf(x.z), f2bf(x.w)};
    __builtin_nontemporal_store(pb, (v4u16*)Pb1w + (size_t)u * 32 + j);
  }

  // chunk l2-norm of x (8-lane factor group)
  float ss = x.x * x.x + x.y * x.y + x.z * x.z + x.w * x.w;
  ss += __shfl_xor(ss, 1, 64);
  ss += __shfl_xor(ss, 2, 64);
  ss += __shfl_xor(ss, 4, 64);
  const float inv = 1.f / fmaxf(sqrtf(ss), 1e-12f);
  const float4 xn = make_float4(x.x * inv, x.y * inv, x.z * inv, x.w * inv);
  if (MODE == 1 && half == 0) {
    v4u16 tb = {f2bf(tanhf(xn.x)), f2bf(tanhf(xn.y)), f2bf(tanhf(xn.z)), f2bf(tanhf(xn.w))};
    __builtin_nontemporal_store(tb, (v4u16*)Tnb1w + (size_t)u * 32 + j);
  }

  // loop 2: A[p][f] += dot(xn_chunk, Tnb[t]_chunk)  (sequential A writes, no atomics)
  int q = beg + half;
  for (; q + 6 < end; q += 8) {                // manual unroll x4
    const int t0 = csr_t[q],     t1 = csr_t[q + 2];
    const int t2 = csr_t[q + 4], t3 = csr_t[q + 6];
    const ushort4 b0 = Tnb4[(size_t)t0 * 32 + j];
    const ushort4 b1 = Tnb4[(size_t)t1 * 32 + j];
    const ushort4 b2 = Tnb4[(size_t)t2 * 32 + j];
    const ushort4 b3 = Tnb4[(size_t)t3 * 32 + j];
    float s0 = xn.x * bf2f(b0.x) + xn.y * bf2f(b0.y) + xn.z * bf2f(b0.z) + xn.w * bf2f(b0.w);
    float s1 = xn.x * bf2f(b1.x) + xn.y * bf2f(b1.y) + xn.z * bf2f(b1.z) + xn.w * bf2f(b1.w);
    float s2 = xn.x * bf2f(b2.x) + xn.y * bf2f(b2.y) + xn.z * bf2f(b2.z) + xn.w * bf2f(b2.w);
    float s3 = xn.x * bf2f(b3.x) + xn.y * bf2f(b3.y) + xn.z * bf2f(b3.z) + xn.w * bf2f(b3.w);
    #pragma unroll
    for (int m = 1; m < 8; m <<= 1) {
      s0 += __shfl_xor(s0, m, 64); s1 += __shfl_xor(s1, m, 64);
      s2 += __shfl_xor(s2, m, 64); s3 += __shfl_xor(s3, m, 64);
    }
    if ((j & 7) == 0) {
      if (FIRST) {
        A[(size_t)q * 4 + f] = 1.f + s0;
        A[(size_t)(q + 2) * 4 + f] = 1.f + s1;
        A[(size_t)(q + 4) * 4 + f] = 1.f + s2;
        A[(size_t)(q + 6) * 4 + f] = 1.f + s3;
      } else {
        A[(size_t)q * 4 + f] += s0;
        A[(size_t)(q + 2) * 4 + f] += s1;
        A[(size_t)(q + 4) * 4 + f] += s2;
        A[(size_t)(q + 6) * 4 + f] += s3;
      }
    }
  }
  for (; q < end; q += 2) {                    // tail
    const int tn = csr_t[q];
    const ushort4 tb = Tnb4[(size_t)tn * 32 + j];
    float s = xn.x * bf2f(tb.x) + xn.y * bf2f(tb.y) + xn.z * bf2f(tb.z) + xn.w * bf2f(tb.w);
    s += __shfl_xor(s, 1, 64);
    s += __shfl_xor(s, 2, 64);
    s += __shfl_xor(s, 4, 64);
    if ((j & 7) == 0) {
      if (FIRST) A[(size_t)q * 4 + f] = 1.f + s;
      else       A[(size_t)q * 4 + f] += s;
    }
  }
}

extern "C" void kernel_launch(void* const* d_in, const int* in_sizes, int n_in,
                              void* d_out, int out_size, void* d_ws, size_t ws_size,
                              hipStream_t stream) {
  const float* ue = (const float*)d_in[0];
  const float* ie = (const float*)d_in[1];
  const int* h = (const int*)d_in[2];
  const int* t = (const int*)d_in[3];
  float* out = (float*)d_out;
  char* ws = (char*)d_ws;

  size_t off = 0;
  auto alloc = [&](size_t bytes) -> void* {
    void* p = ws + off;
    off += (bytes + 255) & ~size_t(255);
    return p;
  };
  float* ego0  = (float*)alloc(sizeof(float) * (size_t)NNODES * EMBD);  // 51.2 MB
  float* ego1  = (float*)alloc(sizeof(float) * (size_t)NNODES * EMBD);  // 51.2 MB
  float* A     = (float*)alloc(sizeof(float) * 4 * (size_t)NEDGE);      // 32  MB (CSR order)
  unsigned short* c = (unsigned short*)alloc(sizeof(unsigned short) * 4 * (size_t)NEDGE); // 16 MB (bf16)
  float* dvA   = (float*)alloc(sizeof(float) * NNODES * 4);             // 1.6 MB (ping)
  float* dvB   = (float*)alloc(sizeof(float) * NNODES * 4);             // 1.6 MB (pong)
  int* row_ptr = (int*)alloc(sizeof(int) * (NNODES + 1));
  int* cur     = (int*)alloc(sizeof(int) * NNODES);
  int* part    = (int*)alloc(sizeof(int) * NNODES);
  int* bsum    = (int*)alloc(sizeof(int) * 128);
  int* boff    = (int*)alloc(sizeof(int) * 128);
  int* csr_t   = (int*)alloc(sizeof(int) * NEDGE);                      // 8 MB

  // bf16 gather tables live in d_out (each half = 51.2 MB = Pb(25.6) + Tnb(25.6)).
  // Layer-1 tables in o1 (dead by pass 3, which overwrites o1);
  // layer-2 tables in o2 (read during pass 3; o2 refilled by the final d2d copy).
  float* o1 = out;
  float* o2 = out + (size_t)NNODES * EMBD;
  ushort4* Pb0  = (ushort4*)o1;
  ushort4* Tnb0 = (ushort4*)((char*)o1 + sizeof(unsigned short) * (size_t)NNODES * EMBD);
  ushort4* Pb1  = (ushort4*)o2;
  ushort4* Tnb1 = (ushort4*)((char*)o2 + sizeof(unsigned short) * (size_t)NNODES * EMBD);

  // setup (once per call)
  init_k<<<(NNODES + 7) / 8, 256, 0, stream>>>((const float4*)ue, (const float4*)ie,
                                               (float4*)ego0, Pb0, Tnb0);
  hipMemsetAsync(cur, 0, sizeof(int) * NNODES, stream);
  hist_k<<<2048, 256, 0, stream>>>(h, cur);
  scan1_k<<<NSCAN, 1024, 0, stream>>>(cur, part, bsum);
  scan2_k<<<1, 128, 0, stream>>>(bsum, boff);
  scan3_k<<<NSCAN, 1024, 0, stream>>>(part, boff, cur, row_ptr, dvA);
  hipMemsetAsync(cur, 0, sizeof(int) * NNODES, stream);
  fill_k<<<2048, 256, 0, stream>>>(h, t, row_ptr, cur, csr_t);

  // pass 0: score (analytic softmax=0.25, dv from counts)  [layer-1 tables]
  // pass 1: deg_sm(A)->c,dvB; score + Q=ego1 + Pb1/Tnb1    [layer-1 tables]
  // pass 2: deg_sm(A)->c,dvA; score                        [layer-2 tables]
  // pass 3: deg_sm(A)->c,dvB; mean output -> o1            [layer-2 tables]
  prop_k<0, true><<<NNODES / 4, 256, 0, stream>>>(
      Pb0, (float4*)ego1, dvA, row_ptr, csr_t, c, A, Tnb0,
      (const float4*)ego0, (const float4*)ego1, (float4*)o1, Pb1, Tnb1);

  deg_sm_k<<<(NNODES + 15) / 16, 256, 0, stream>>>(A, row_ptr, c, dvB);
  prop_k<1, false><<<NNODES / 4, 256, 0, stream>>>(
      Pb0, (float4*)ego1, dvB, row_ptr, csr_t, c, A, Tnb0,
      (const float4*)ego0, (const float4*)ego1, (float4*)o1, Pb1, Tnb1);

  deg_sm_k<<<(NNODES + 15) / 16, 256, 0, stream>>>(A, row_ptr, c, dvA);
  prop_k<0, false><<<NNODES / 4, 256, 0, stream>>>(
      Pb1, (float4*)ego1, dvA, row_ptr, csr_t, c, A, Tnb1,
      (const float4*)ego0, (const float4*)ego1, (float4*)o1, Pb1, Tnb1);

  deg_sm_k<<<(NNODES + 15) / 16, 256, 0, stream>>>(A, row_ptr, c, dvB);
  prop_k<2, false><<<NNODES / 4, 256, 0, stream>>>(
      Pb1, (float4*)ego1, dvB, row_ptr, csr_t, c, A, Tnb1,
      (const float4*)ego0, (const float4*)ego1, (float4*)o1, Pb1, Tnb1);

  // duplicate (u_g, i_g) into the second output pair
  hipMemcpyAsync(o2, o1, sizeof(float) * (size_t)NNODES * EMBD,
                 hipMemcpyDeviceToDevice, stream);
}